// Round 4
// baseline (463987.158 us; speedup 1.0000x reference)
//
#include <hip/hip_runtime.h>
#include <math.h>

#define T_STEPS 22550
#define NWG 32
#define NTHR 512

typedef unsigned long long ull;

// ---- workspace layout (float offsets) ----
#define OF_AM2   64                        // 2 parity banks x 32 WG x 16 u64 = 2048 floats
#define OF_H1E   (OF_AM2 + 2048)           // 256 u64 = 512 floats
#define OF_H2E   (OF_H1E + 512)            // 512 u64 = 1024 floats
#define OF_PLC   (OF_H2E + 1024)           // 32 x 256 u64 = 16384 floats
#define OF_O3P   (OF_PLC + 16384)          // 32 x 512 u64 = 32768 floats
#define OF_SLOTEND (OF_O3P + 32768)        // = 52800
#define OF_BUFA  OF_SLOTEND                // conv stage0 out [128][412]
#define OF_BUFB  (OF_BUFA + 128*412)       // conv stage1 out [128][2052]
#define OF_COND  (OF_BUFB + 128*2052)      // cond [T][128]

__global__ void k_init(float* ws){
  int i = blockIdx.x*blockDim.x + threadIdx.x;
  if (i < (OF_SLOTEND - OF_AM2)) ws[OF_AM2 + i] = 0.f;
}

// transposed conv (lhs_dilation=sc), padding e, then relu.
// mode 0: y[c][j]; mode 1: write cond[t=j-1][c] (crop [1:-1], transpose)
__global__ void k_upconv(const float* __restrict__ x, int instride, int inoff,
                         const float* __restrict__ w, const float* __restrict__ b,
                         float* __restrict__ y, int Cin, int Lin, int K, int sc, int e,
                         int Lout, int mode)
{
  int j = blockIdx.x*blockDim.x + threadIdx.x;
  int c = blockIdx.y;
  if (j >= Lout) return;
  float acc = b[c];
  int kstart = ((e - j) % sc + sc) % sc;
  for (int i = 0; i < Cin; ++i){
    const float* wci = w + (c*Cin + i)*K;
    const float* xi  = x + i*instride + inoff;
    for (int k = kstart; k < K; k += sc){
      int qd = j - e + k;
      if (qd >= 0){
        int qq = qd / sc;
        if (qq < Lin) acc += wci[k]*xi[qq];
      }
    }
  }
  acc = fmaxf(acc, 0.f);
  if (mode == 0) y[c*Lout + j] = acc;
  else { int t = j - 1; if (t >= 0 && t < T_STEPS) y[t*128 + c] = acc; }
}

__device__ __forceinline__ float sigm(float x){ return 1.f/(1.f + expf(-x)); }

__device__ __forceinline__ void pub64(ull* p, ull pk){
  __hip_atomic_store(p, pk, __ATOMIC_RELAXED, __HIP_MEMORY_SCOPE_AGENT);
}
__device__ __forceinline__ ull ld64(ull* p){
  return __hip_atomic_load(p, __ATOMIC_RELAXED, __HIP_MEMORY_SCOPE_AGENT);
}
__device__ __forceinline__ float spin_get(ull* p, unsigned tag){
  ull pk = ld64(p);
  while ((unsigned)pk != tag) pk = ld64(p);
  return __uint_as_float((unsigned)(pk >> 32));
}

__launch_bounds__(NTHR)
__global__ void k_wavernn(const float* __restrict__ Wx, const float* __restrict__ bx,
                          const float* __restrict__ Wh, const float* __restrict__ bh,
                          const float* __restrict__ O1w, const float* __restrict__ O1b,
                          const float* __restrict__ O2w, const float* __restrict__ O2b,
                          const float* __restrict__ O3w, const float* __restrict__ O3b,
                          const float* __restrict__ O4w, const float* __restrict__ O4b,
                          float* ws, float* __restrict__ out)
{
  __shared__ __align__(16) float h_s[512];
  __shared__ __align__(16) float m_s[128];
  __shared__ __align__(16) float h1c_s[256];
  __shared__ __align__(16) float o_s[512];
  __shared__ __align__(16) float logit_s[256];
  __shared__ float hg_s[48], xgb_s[48], xg1_s[48];
  __shared__ float o1own_s[16], h2own_s[16];
  __shared__ float red_s[8], sc_s[8];
  __shared__ float wc0_s[48], wc1_s[48], wc2_s[48], bx_s[48], bh_s[48];

  const int tid = threadIdx.x, g = blockIdx.x;
  ull* am2 = (ull*)(ws + OF_AM2);
  ull* h1e = (ull*)(ws + OF_H1E);
  ull* h2e = (ull*)(ws + OF_H2E);
  ull* plc = (ull*)(ws + OF_PLC);
  ull* o3p = (ull*)(ws + OF_O3P);
  const float* cond = ws + OF_COND;
  float* out_samp = out;
  float* out_log  = out + T_STEPS;

  // ---- preloads ----
  // gate metadata (WG g owns h elems {g+32i}; gate rows {gate*512 + elem})
  if (tid < 48){
    int row = (tid>>4)*512 + g + 32*(tid&15);
    wc0_s[tid] = Wx[(size_t)row*131 + 0];
    wc1_s[tid] = Wx[(size_t)row*131 + 1];
    wc2_s[tid] = Wx[(size_t)row*131 + 2];
    bx_s[tid]  = bx[row];
    bh_s[tid]  = bh[row];
  }
  // O1: 16 rows/WG {g+32*m16}, 32 lanes/row, 8 cols/lane
  const int m16 = tid>>5, l32 = tid&31;
  const int rowO1 = g + 32*m16;
  float wO1r[8];
  #pragma unroll
  for (int k=0;k<8;++k) wO1r[k] = O1w[(size_t)rowO1*256 + l32 + 32*k];
  const float bO1r = O1b[rowO1];
  // pl_c: O2 column-slice for own o1 rows (tid<256 each owns one logit)
  float wPC[16]; float cb2 = 0.f;
  if (tid < 256){
    #pragma unroll
    for (int m=0;m<16;++m) wPC[m] = O2w[(size_t)tid*512 + g + 32*m];
    cb2 = O2b[tid];
  }
  // o3 partial: O3 column-slice for own upper h2 elems (each thread owns o3[tid])
  float wPF[8];
  #pragma unroll
  for (int j=0;j<8;++j) wPF[j] = O3w[(size_t)tid*256 + g + 32*j];
  const float bO3r = O3b[tid];
  // O4: 8 rows/WG {g+32*mO4}, 64 lanes/row, 8 cols/lane
  const int mO4 = tid>>6, l64 = tid&63;
  const int rowO4 = g + 32*mO4;
  float wO4r[8];
  #pragma unroll
  for (int k=0;k<8;++k) wO4r[k] = O4w[(size_t)rowO4*512 + l64 + 64*k];
  const float bO4r = O4b[rowO4];

  h_s[tid] = 0.f;
  if (tid < 128) m_s[tid] = cond[tid];
  if (tid == 0){ sc_s[0] = 0.f; sc_s[1] = 0.f; }
  __syncthreads();

  // hg = Wh@h + bh ; xgb = Wx[:,3:]@m + bx  (48 rows x 8 lanes, XOR-swizzled LDS reads)
  #define COMPUTE_HX() do { \
    if (tid < 384){ \
      const int li_ = tid>>3, p_ = tid&7; \
      const int row_ = (li_>>4)*512 + g + 32*(li_&15); \
      const float4* W4 = (const float4*)(Wh + (size_t)row_*512); \
      const float4* H4 = (const float4*)h_s; \
      float aH = 0.f; \
      _Pragma("unroll") \
      for (int kk=0; kk<16; ++kk){ \
        int f_ = p_*16 + (kk ^ p_); \
        float4 w = W4[f_], v = H4[f_]; \
        aH += w.x*v.x + w.y*v.y + w.z*v.z + w.w*v.w; \
      } \
      const float* WxR = Wx + (size_t)row_*131 + 3 + p_*16; \
      const float* mR  = m_s + p_*16; \
      float aX = 0.f; \
      _Pragma("unroll") \
      for (int kk=0; kk<16; ++kk) aX += WxR[kk]*mR[kk]; \
      aH += __shfl_xor(aH,1); aH += __shfl_xor(aH,2); aH += __shfl_xor(aH,4); \
      aX += __shfl_xor(aX,1); aX += __shfl_xor(aX,2); aX += __shfl_xor(aX,4); \
      if (p_ == 0){ hg_s[li_] = aH + bh_s[li_]; xgb_s[li_] = aX + bx_s[li_]; } \
    } } while(0)

  COMPUTE_HX();

  for (int t = 0; t < T_STEPS; ++t){
    const unsigned tag = (unsigned)(t + 1);
    __syncthreads();                        // hg/xgb/sc_s ready

    // (a) xg1 = xgb + c*w0 + f*w1
    if (tid < 48) xg1_s[tid] = xgb_s[tid] + sc_s[0]*wc0_s[tid] + sc_s[1]*wc1_s[tid];
    __syncthreads();

    // (b) GRU1 gates for own lower-8 elems, publish h1
    if (tid < 8){
      float r = sigm(xg1_s[tid]     + hg_s[tid]);
      float z = sigm(xg1_s[16+tid]  + hg_s[16+tid]);
      float n = tanhf(xg1_s[32+tid] + r*hg_s[32+tid]);
      float h1 = (1.f - z)*n + z*h_s[g + 32*tid];
      pub64(&h1e[g*8 + tid], ((ull)__float_as_uint(h1) << 32) | tag);
    }
    // (c) gather full h1[0:256]
    if (tid < 256) h1c_s[tid] = spin_get(&h1e[(tid & 31)*8 + (tid >> 5)], tag);
    __syncthreads();

    // (d) o1 own 16 rows
    {
      float acc = 0.f;
      #pragma unroll
      for (int k=0;k<8;++k) acc += wO1r[k]*h1c_s[l32 + 32*k];
      acc += __shfl_xor(acc,1); acc += __shfl_xor(acc,2); acc += __shfl_xor(acc,4);
      acc += __shfl_xor(acc,8); acc += __shfl_xor(acc,16);
      if (l32 == 0) o1own_s[m16] = fmaxf(acc + bO1r, 0.f);
    }
    __syncthreads();

    // (e) partial c-logits from own o1 rows, publish
    if (tid < 256){
      float s = 0.f;
      #pragma unroll
      for (int m=0;m<16;++m) s += wPC[m]*o1own_s[m];
      pub64(&plc[g*256 + tid], ((ull)__float_as_uint(s) << 32) | tag);
    }
    // (f) gather+sum all 32 partial slabs -> full c-logits (local!)
    if (tid < 256){
      ull v[32];
      #pragma unroll
      for (int g2=0; g2<32; ++g2) v[g2] = ld64(&plc[g2*256 + tid]);
      float s = cb2;
      #pragma unroll
      for (int g2=0; g2<32; ++g2){
        ull pk = v[g2];
        while ((unsigned)pk != tag) pk = ld64(&plc[g2*256 + tid]);
        s += __uint_as_float((unsigned)(pk >> 32));
      }
      logit_s[tid] = s;
    }
    __syncthreads();
    // write our slice of c-logits; local argmax (identical on all WGs)
    if (tid < 8) out_log[(size_t)t*512 + 8*g + tid] = logit_s[8*g + tid];
    if (tid < 64){
      float bv = logit_s[tid]; int bi = tid;
      #pragma unroll
      for (int j=1;j<4;++j){ float v2 = logit_s[tid + 64*j]; if (v2 > bv){ bv = v2; bi = tid + 64*j; } }
      #pragma unroll
      for (int off=32; off>=1; off>>=1){
        float ov = __shfl_xor(bv,off); int oi = __shfl_xor(bi,off);
        if (ov > bv || (ov == bv && oi < bi)){ bv = ov; bi = oi; }
      }
      if (tid == 0){ sc_s[2] = (float)bi; sc_s[3] = (float)bi/127.5f - 1.f; }
    }
    __syncthreads();

    // (h) GRU2 for all 16 own elems, publish h2 (thin)
    if (tid < 16){
      float cn = sc_s[3];
      float r = sigm(xg1_s[tid]     + cn*wc2_s[tid]     + hg_s[tid]);
      float z = sigm(xg1_s[16+tid]  + cn*wc2_s[16+tid]  + hg_s[16+tid]);
      float n = tanhf(xg1_s[32+tid] + cn*wc2_s[32+tid]  + r*hg_s[32+tid]);
      float h2 = (1.f - z)*n + z*h_s[g + 32*tid];
      h2own_s[tid] = h2;
      pub64(&h2e[g*16 + tid], ((ull)__float_as_uint(h2) << 32) | tag);
    }
    __syncthreads();
    // (h2) o3 partial from own upper-8 h2 elems, publish
    {
      float s = 0.f;
      #pragma unroll
      for (int j=0;j<8;++j) s += wPF[j]*h2own_s[8 + j];
      pub64(&o3p[g*512 + tid], ((ull)__float_as_uint(s) << 32) | tag);
    }
    // (k') gather full h2 into h_s (parallel wait with o3p); next cond row
    h_s[tid] = spin_get(&h2e[(tid & 31)*16 + (tid >> 5)], tag);
    if (tid < 128 && t + 1 < T_STEPS) m_s[tid] = cond[(size_t)(t+1)*128 + tid];
    // (i) gather+sum o3 partials -> full o3 (local)
    {
      ull v[32];
      #pragma unroll
      for (int g2=0; g2<32; ++g2) v[g2] = ld64(&o3p[g2*512 + tid]);
      float s = bO3r;
      #pragma unroll
      for (int g2=0; g2<32; ++g2){
        ull pk = v[g2];
        while ((unsigned)pk != tag) pk = ld64(&o3p[g2*512 + tid]);
        s += __uint_as_float((unsigned)(pk >> 32));
      }
      o_s[tid] = fmaxf(s, 0.f);
    }
    __syncthreads();

    // (j) O4 own 8 rows, publish per-WG row max (the only f trip, hidden below)
    {
      float acc = 0.f;
      #pragma unroll
      for (int k=0;k<8;++k) acc += wO4r[k]*o_s[l64 + 64*k];
      acc += __shfl_xor(acc,1); acc += __shfl_xor(acc,2); acc += __shfl_xor(acc,4);
      acc += __shfl_xor(acc,8); acc += __shfl_xor(acc,16); acc += __shfl_xor(acc,32);
      if (l64 == 0){
        float v = acc + bO4r;
        out_log[(size_t)t*512 + 256 + rowO4] = v;
        red_s[mO4] = v;
      }
    }
    __syncthreads();
    if (tid == 0){
      float bv = red_s[0]; int bi = g;          // rows ascend with m -> strict > = first max
      #pragma unroll
      for (int m=1;m<8;++m){ float v = red_s[m]; if (v > bv){ bv = v; bi = g + 32*m; } }
      pub64(&am2[((t & 1)*NWG + g)*16],
            ((ull)__float_as_uint(bv) << 32) | ((ull)(unsigned)bi << 24) | tag);
    }

    // (l) next step's hg/xgb — overlaps the f-trip
    COMPUTE_HX();

    // (m) gather f maxima (parity-banked slots), finish step
    if (tid < 32){
      ull* sl = &am2[((t & 1)*NWG + tid)*16];
      ull pk = ld64(sl);
      while ((unsigned)(pk & 0xFFFFFFu) != tag) pk = ld64(sl);
      float bv = __uint_as_float((unsigned)(pk >> 32));
      int   bi = (int)((pk >> 24) & 0xFFu);
      #pragma unroll
      for (int off=16; off>=1; off>>=1){
        float ov = __shfl_xor(bv,off); int oi = __shfl_xor(bi,off);
        if (ov > bv || (ov == bv && oi < bi)){ bv = ov; bi = oi; }
      }
      if (tid == 0){
        sc_s[0] = sc_s[3];                       // c carry
        sc_s[1] = (float)bi/127.5f - 1.f;        // f carry
        if (g == 0) out_samp[t] = (sc_s[2]*256.f + (float)bi)/32767.5f - 1.f;
      }
    }
    // loop-top __syncthreads() publishes hg/xgb/sc
  }
}

extern "C" void kernel_launch(void* const* d_in, const int* in_sizes, int n_in,
                              void* d_out, int out_size, void* d_ws, size_t ws_size,
                              hipStream_t stream)
{
  const float* mels  = (const float*)d_in[0];
  const float* up_w0 = (const float*)d_in[1]; const float* up_b0 = (const float*)d_in[2];
  const float* up_w1 = (const float*)d_in[3]; const float* up_b1 = (const float*)d_in[4];
  const float* up_w2 = (const float*)d_in[5]; const float* up_b2 = (const float*)d_in[6];
  const float* Wx  = (const float*)d_in[7];  const float* bx  = (const float*)d_in[8];
  const float* Wh  = (const float*)d_in[9];  const float* bh  = (const float*)d_in[10];
  const float* O1w = (const float*)d_in[11]; const float* O1b = (const float*)d_in[12];
  const float* O2w = (const float*)d_in[13]; const float* O2b = (const float*)d_in[14];
  const float* O3w = (const float*)d_in[15]; const float* O3b = (const float*)d_in[16];
  const float* O4w = (const float*)d_in[17]; const float* O4b = (const float*)d_in[18];
  float* ws  = (float*)d_ws;
  float* out = (float*)d_out;

  k_init<<<((OF_SLOTEND-OF_AM2) + 255)/256, 256, 0, stream>>>(ws);

  // upsample: 84 -> 412 -> 2052 -> 22552 (crop [1:-1] -> cond[22550][128])
  k_upconv<<<dim3((412  +127)/128, 128), 128, 0, stream>>>(mels,        86,   1, up_w0, up_b0,
            ws+OF_BUFA,  80,   84, 11,  5, 3,   412, 0);
  k_upconv<<<dim3((2052 +127)/128, 128), 128, 0, stream>>>(ws+OF_BUFA, 412,   0, up_w1, up_b1,
            ws+OF_BUFB, 128,  412, 11,  5, 3,  2052, 0);
  k_upconv<<<dim3((22552+127)/128, 128), 128, 0, stream>>>(ws+OF_BUFB, 2052,  0, up_w2, up_b2,
            ws+OF_COND, 128, 2052, 23, 11, 6, 22552, 1);

  k_wavernn<<<NWG, NTHR, 0, stream>>>(Wx, bx, Wh, bh, O1w, O1b, O2w, O2b,
                                      O3w, O3b, O4w, O4b, ws, out);
}

// Round 5
// 389239.478 us; speedup vs baseline: 1.1920x; 1.1920x over previous
//
#include <hip/hip_runtime.h>
#include <math.h>

#define T_STEPS 22550
#define NWG 32
#define NTHR 256

typedef unsigned long long ull;

// ---- mailbox layout (u64 units inside one consumer region) ----
#define MB_H1   0        // 256 slots [elem]
#define MB_O1   256      // 512 slots [row]
#define MB_H2   768      // 512 slots [elem]
#define MB_O3   1280     // 512 slots [row]
#define MB_AM1  1792     // 32 slots [producer g]
#define MB_AM2  1824     // 2 parity banks x 32
#define MB_SZ   2048     // padded region size (16KB)

// ---- workspace layout (float offsets) ----
#define OF_MB    64
#define OF_SLOTEND (OF_MB + NWG*MB_SZ*2)     // 131136
#define OF_BUFA  OF_SLOTEND                  // conv stage0 out [128][412]
#define OF_BUFB  (OF_BUFA + 128*412)         // conv stage1 out [128][2052]
#define OF_COND  (OF_BUFB + 128*2052)        // cond [T][128]

__global__ void k_init(float* ws){
  int i = blockIdx.x*blockDim.x + threadIdx.x;
  if (i < NWG*MB_SZ*2) ws[OF_MB + i] = 0.f;
}

// transposed conv (lhs_dilation=sc), padding e, then relu.
// mode 0: y[c][j]; mode 1: write cond[t=j-1][c] (crop [1:-1], transpose)
__global__ void k_upconv(const float* __restrict__ x, int instride, int inoff,
                         const float* __restrict__ w, const float* __restrict__ b,
                         float* __restrict__ y, int Cin, int Lin, int K, int sc, int e,
                         int Lout, int mode)
{
  int j = blockIdx.x*blockDim.x + threadIdx.x;
  int c = blockIdx.y;
  if (j >= Lout) return;
  float acc = b[c];
  int kstart = ((e - j) % sc + sc) % sc;
  for (int i = 0; i < Cin; ++i){
    const float* wci = w + (c*Cin + i)*K;
    const float* xi  = x + i*instride + inoff;
    for (int k = kstart; k < K; k += sc){
      int qd = j - e + k;
      if (qd >= 0){
        int qq = qd / sc;
        if (qq < Lin) acc += wci[k]*xi[qq];
      }
    }
  }
  acc = fmaxf(acc, 0.f);
  if (mode == 0) y[c*Lout + j] = acc;
  else { int t = j - 1; if (t >= 0 && t < T_STEPS) y[t*128 + c] = acc; }
}

__device__ __forceinline__ float sigm(float x){ return 1.f/(1.f + expf(-x)); }

__device__ __forceinline__ void pub64(ull* p, ull pk){
  __hip_atomic_store(p, pk, __ATOMIC_RELAXED, __HIP_MEMORY_SCOPE_AGENT);
}
__device__ __forceinline__ ull ld64(ull* p){
  return __hip_atomic_load(p, __ATOMIC_RELAXED, __HIP_MEMORY_SCOPE_AGENT);
}
__device__ __forceinline__ float spin_data(ull* p, unsigned tag){
  ull pk = ld64(p);
  while ((unsigned)pk != tag) pk = ld64(p);
  return __uint_as_float((unsigned)(pk >> 32));
}
__device__ __forceinline__ ull spin_am(ull* p, unsigned tag){
  ull pk = ld64(p);
  while ((unsigned)(pk & 0xFFFFFFu) != tag) pk = ld64(p);
  return pk;
}
__device__ __forceinline__ ull pack_data(float v, unsigned tag){
  return ((ull)__float_as_uint(v) << 32) | (ull)tag;
}

__launch_bounds__(NTHR)
__global__ void k_wavernn(const float* __restrict__ Wx, const float* __restrict__ bx,
                          const float* __restrict__ Wh, const float* __restrict__ bh,
                          const float* __restrict__ O1w, const float* __restrict__ O1b,
                          const float* __restrict__ O2w, const float* __restrict__ O2b,
                          const float* __restrict__ O3w, const float* __restrict__ O3b,
                          const float* __restrict__ O4w, const float* __restrict__ O4b,
                          float* ws, float* __restrict__ out)
{
  __shared__ __align__(16) float h_s[512];
  __shared__ __align__(16) float m_s[128];
  __shared__ __align__(16) float h1c_s[256];
  __shared__ __align__(16) float o_s[512];
  __shared__ float hg_s[48], xgb_s[48], xg1_s[48];
  __shared__ float h1own_s[8], o1own_s[16], h2own_s[16], o3own_s[16];
  __shared__ float red_s[8], sc_s[8];
  __shared__ float wc0_s[48], wc1_s[48], wc2_s[48], bx_s[48], bh_s[48];

  const int tid = threadIdx.x, g = blockIdx.x;
  ull* mb = (ull*)(ws + OF_MB);
  ull* my = mb + (size_t)g*MB_SZ;
  const float* cond = ws + OF_COND;
  float* out_samp = out;
  float* out_log  = out + T_STEPS;

  // ---- preloads ----
  // gate metadata: WG g owns h elems {g+32i}; gate rows {gate*512 + elem}
  if (tid < 48){
    int row = (tid>>4)*512 + g + 32*(tid&15);
    wc0_s[tid] = Wx[(size_t)row*131 + 0];
    wc1_s[tid] = Wx[(size_t)row*131 + 1];
    wc2_s[tid] = Wx[(size_t)row*131 + 2];
    bx_s[tid]  = bx[row];
    bh_s[tid]  = bh[row];
  }
  // O1/O3: 16 rows/WG {g+32*m16}, 16 lanes/row, 16 contiguous cols/lane
  const int m16 = tid>>4, c16 = tid&15;
  const int rowO1 = g + 32*m16;
  float wO1r[16], wO3r[16];
  #pragma unroll
  for (int k=0;k<16;++k){
    wO1r[k] = O1w[(size_t)rowO1*256 + c16*16 + k];
    wO3r[k] = O3w[(size_t)rowO1*256 + c16*16 + k];
  }
  const float bO1r = O1b[rowO1], bO3r = O3b[rowO1];
  // O2/O4: 8 rows/WG {g+32*m8}, 32 lanes/row, stride-32 cols
  const int m8 = tid>>5, l32 = tid&31;
  const int row2 = g + 32*m8;
  float wO2r[16], wO4r[16];
  #pragma unroll
  for (int k=0;k<16;++k){
    wO2r[k] = O2w[(size_t)row2*512 + l32 + 32*k];
    wO4r[k] = O4w[(size_t)row2*512 + l32 + 32*k];
  }
  const float bO2 = O2b[row2], bO4 = O4b[row2];

  h_s[tid] = 0.f; h_s[tid+256] = 0.f;
  if (tid < 128) m_s[tid] = cond[tid];
  if (tid == 0){ sc_s[0] = 0.f; sc_s[1] = 0.f; }
  __syncthreads();

  // hg = Wh@h + bh ; xgb = Wx[:,3:]@m + bx   (48 rows x 4 lanes, bank-swizzled)
  #define COMPUTE_HX() do { \
    if (tid < 192){ \
      const int li_ = tid>>2, q_ = tid&3; \
      const int row_ = (li_>>4)*512 + g + 32*(li_&15); \
      const float4* W4 = (const float4*)(Wh + (size_t)row_*512); \
      const float4* H4 = (const float4*)h_s; \
      float aH = 0.f; \
      _Pragma("unroll") \
      for (int kk=0; kk<32; ++kk){ \
        int f_ = q_*32 + ((kk + 2*q_) & 31); \
        float4 w = W4[f_], v = H4[f_]; \
        aH += w.x*v.x + w.y*v.y + w.z*v.z + w.w*v.w; \
      } \
      const float* WxR = Wx + (size_t)row_*131 + 3; \
      float aX = 0.f; \
      _Pragma("unroll") \
      for (int kk=0; kk<32; ++kk){ \
        int f_ = q_*32 + ((kk + 8*q_) & 31); \
        aX += WxR[f_]*m_s[f_]; \
      } \
      aH += __shfl_xor(aH,1); aH += __shfl_xor(aH,2); \
      aX += __shfl_xor(aX,1); aX += __shfl_xor(aX,2); \
      if (q_ == 0){ hg_s[li_] = aH + bh_s[li_]; xgb_s[li_] = aX + bx_s[li_]; } \
    } } while(0)

  COMPUTE_HX();

  for (int t = 0; t < T_STEPS; ++t){
    const unsigned tag = (unsigned)(t + 1);
    __syncthreads();                        // hg/xgb/sc_s ready

    // (a) xg1 = xgb + c*w0 + f*w1
    if (tid < 48) xg1_s[tid] = xgb_s[tid] + sc_s[0]*wc0_s[tid] + sc_s[1]*wc1_s[tid];
    __syncthreads();

    // (b) GRU1 gates for own lower-8 elems
    if (tid < 8){
      float r = sigm(xg1_s[tid]     + hg_s[tid]);
      float z = sigm(xg1_s[16+tid]  + hg_s[16+tid]);
      float n = tanhf(xg1_s[32+tid] + r*hg_s[32+tid]);
      h1own_s[tid] = (1.f - z)*n + z*h_s[g + 32*tid];
    }
    __syncthreads();
    {  // scatter h1 to all consumer mailboxes (256 stores, 1/thread)
      int cons = tid >> 3, i = tid & 7;
      pub64(mb + (size_t)cons*MB_SZ + MB_H1 + (g + 32*i), pack_data(h1own_s[i], tag));
    }
    // (c) gather full h1[0:256] from OWN mailbox
    if (tid < 256) h1c_s[tid] = spin_data(my + MB_H1 + tid, tag);
    __syncthreads();

    // (d) o1: own 16 rows
    {
      float acc = 0.f;
      #pragma unroll
      for (int k=0;k<16;++k) acc += wO1r[k]*h1c_s[c16*16 + k];
      acc += __shfl_xor(acc,1); acc += __shfl_xor(acc,2);
      acc += __shfl_xor(acc,4); acc += __shfl_xor(acc,8);
      if (c16 == 0) o1own_s[m16] = fmaxf(acc + bO1r, 0.f);
    }
    __syncthreads();
    {  // scatter o1 (512 stores, 2/thread)
      #pragma unroll
      for (int r=0;r<2;++r){
        int idx = tid + 256*r, cons = idx >> 4, mm = idx & 15;
        pub64(mb + (size_t)cons*MB_SZ + MB_O1 + (g + 32*mm), pack_data(o1own_s[mm], tag));
      }
    }
    // (e) gather o1
    o_s[tid]       = spin_data(my + MB_O1 + tid, tag);
    o_s[tid + 256] = spin_data(my + MB_O1 + tid + 256, tag);
    __syncthreads();

    // (f) O2 own 8 rows -> red_s; wave0 reduces + scatters am1
    {
      float acc = 0.f;
      #pragma unroll
      for (int k=0;k<16;++k) acc += wO2r[k]*o_s[l32 + 32*k];
      acc += __shfl_xor(acc,1); acc += __shfl_xor(acc,2); acc += __shfl_xor(acc,4);
      acc += __shfl_xor(acc,8); acc += __shfl_xor(acc,16);
      if (l32 == 0){ float v = acc + bO2; out_log[(size_t)t*512 + row2] = v; red_s[m8] = v; }
    }
    __syncthreads();
    if (tid < 32){
      float bv = (tid < 8) ? red_s[tid] : -3.4e38f;
      int   bi = (tid < 8) ? (g + 32*tid) : (1<<30);
      #pragma unroll
      for (int off=1; off<=4; off<<=1){
        float ov = __shfl_xor(bv,off); int oi = __shfl_xor(bi,off);
        if (ov > bv || (ov == bv && oi < bi)){ bv = ov; bi = oi; }
      }
      float bv0 = __shfl(bv, 0); int bi0 = __shfl(bi, 0);
      ull pk = ((ull)__float_as_uint(bv0) << 32) | ((ull)(unsigned)bi0 << 24) | tag;
      pub64(mb + (size_t)tid*MB_SZ + MB_AM1 + g, pk);
    }
    // (g) gather am1, global argmax -> c
    if (tid < 32){
      ull pk = spin_am(my + MB_AM1 + tid, tag);
      float bv = __uint_as_float((unsigned)(pk >> 32));
      int   bi = (int)((pk >> 24) & 0xFFu);
      #pragma unroll
      for (int off=16; off>=1; off>>=1){
        float ov = __shfl_xor(bv,off); int oi = __shfl_xor(bi,off);
        if (ov > bv || (ov == bv && oi < bi)){ bv = ov; bi = oi; }
      }
      if (tid == 0){ sc_s[2] = (float)bi; sc_s[3] = (float)bi/127.5f - 1.f; }
    }
    __syncthreads();

    // (h) GRU2 for all 16 own elems
    if (tid < 16){
      float cn = sc_s[3];
      float r = sigm(xg1_s[tid]     + cn*wc2_s[tid]     + hg_s[tid]);
      float z = sigm(xg1_s[16+tid]  + cn*wc2_s[16+tid]  + hg_s[16+tid]);
      float n = tanhf(xg1_s[32+tid] + cn*wc2_s[32+tid]  + r*hg_s[32+tid]);
      h2own_s[tid] = (1.f - z)*n + z*h_s[g + 32*tid];
    }
    __syncthreads();                        // also: last read of old h_s done
    {  // scatter h2 (512 stores)
      #pragma unroll
      for (int r=0;r<2;++r){
        int idx = tid + 256*r, cons = idx >> 4, i = idx & 15;
        pub64(mb + (size_t)cons*MB_SZ + MB_H2 + (g + 32*i), pack_data(h2own_s[i], tag));
      }
    }
    // (i) gather h2 into h_s; next cond row
    h_s[tid]       = spin_data(my + MB_H2 + tid, tag);
    h_s[tid + 256] = spin_data(my + MB_H2 + tid + 256, tag);
    if (tid < 128 && t + 1 < T_STEPS) m_s[tid] = cond[(size_t)(t+1)*128 + tid];
    __syncthreads();

    // (j) o3: own 16 rows from h2 upper half
    {
      float acc = 0.f;
      #pragma unroll
      for (int k=0;k<16;++k) acc += wO3r[k]*h_s[256 + c16*16 + k];
      acc += __shfl_xor(acc,1); acc += __shfl_xor(acc,2);
      acc += __shfl_xor(acc,4); acc += __shfl_xor(acc,8);
      if (c16 == 0) o3own_s[m16] = fmaxf(acc + bO3r, 0.f);
    }
    __syncthreads();
    {  // scatter o3 (512 stores)
      #pragma unroll
      for (int r=0;r<2;++r){
        int idx = tid + 256*r, cons = idx >> 4, mm = idx & 15;
        pub64(mb + (size_t)cons*MB_SZ + MB_O3 + (g + 32*mm), pack_data(o3own_s[mm], tag));
      }
    }
    // (k) gather o3
    o_s[tid]       = spin_data(my + MB_O3 + tid, tag);
    o_s[tid + 256] = spin_data(my + MB_O3 + tid + 256, tag);
    __syncthreads();

    // (l) O4 own 8 rows -> red_s; wave0 reduces + scatters am2 (parity bank)
    {
      float acc = 0.f;
      #pragma unroll
      for (int k=0;k<16;++k) acc += wO4r[k]*o_s[l32 + 32*k];
      acc += __shfl_xor(acc,1); acc += __shfl_xor(acc,2); acc += __shfl_xor(acc,4);
      acc += __shfl_xor(acc,8); acc += __shfl_xor(acc,16);
      if (l32 == 0){ float v = acc + bO4; out_log[(size_t)t*512 + 256 + row2] = v; red_s[m8] = v; }
    }
    __syncthreads();
    if (tid < 32){
      float bv = (tid < 8) ? red_s[tid] : -3.4e38f;
      int   bi = (tid < 8) ? (g + 32*tid) : (1<<30);
      #pragma unroll
      for (int off=1; off<=4; off<<=1){
        float ov = __shfl_xor(bv,off); int oi = __shfl_xor(bi,off);
        if (ov > bv || (ov == bv && oi < bi)){ bv = ov; bi = oi; }
      }
      float bv0 = __shfl(bv, 0); int bi0 = __shfl(bi, 0);
      ull pk = ((ull)__float_as_uint(bv0) << 32) | ((ull)(unsigned)bi0 << 24) | tag;
      pub64(mb + (size_t)tid*MB_SZ + MB_AM2 + (t & 1)*32 + g, pk);
    }

    // (m) next step's hg/xgb — overlaps the am2 trip
    COMPUTE_HX();

    // (n) gather am2 -> f, carries, sample
    if (tid < 32){
      ull pk = spin_am(my + MB_AM2 + (t & 1)*32 + tid, tag);
      float bv = __uint_as_float((unsigned)(pk >> 32));
      int   bi = (int)((pk >> 24) & 0xFFu);
      #pragma unroll
      for (int off=16; off>=1; off>>=1){
        float ov = __shfl_xor(bv,off); int oi = __shfl_xor(bi,off);
        if (ov > bv || (ov == bv && oi < bi)){ bv = ov; bi = oi; }
      }
      if (tid == 0){
        sc_s[0] = sc_s[3];                       // c carry
        sc_s[1] = (float)bi/127.5f - 1.f;        // f carry
        if (g == 0) out_samp[t] = (sc_s[2]*256.f + (float)bi)/32767.5f - 1.f;
      }
    }
    // loop-top __syncthreads() publishes hg/xgb/sc
  }
}

extern "C" void kernel_launch(void* const* d_in, const int* in_sizes, int n_in,
                              void* d_out, int out_size, void* d_ws, size_t ws_size,
                              hipStream_t stream)
{
  const float* mels  = (const float*)d_in[0];
  const float* up_w0 = (const float*)d_in[1]; const float* up_b0 = (const float*)d_in[2];
  const float* up_w1 = (const float*)d_in[3]; const float* up_b1 = (const float*)d_in[4];
  const float* up_w2 = (const float*)d_in[5]; const float* up_b2 = (const float*)d_in[6];
  const float* Wx  = (const float*)d_in[7];  const float* bx  = (const float*)d_in[8];
  const float* Wh  = (const float*)d_in[9];  const float* bh  = (const float*)d_in[10];
  const float* O1w = (const float*)d_in[11]; const float* O1b = (const float*)d_in[12];
  const float* O2w = (const float*)d_in[13]; const float* O2b = (const float*)d_in[14];
  const float* O3w = (const float*)d_in[15]; const float* O3b = (const float*)d_in[16];
  const float* O4w = (const float*)d_in[17]; const float* O4b = (const float*)d_in[18];
  float* ws  = (float*)d_ws;
  float* out = (float*)d_out;

  k_init<<<(NWG*MB_SZ*2 + 255)/256, 256, 0, stream>>>(ws);

  // upsample: 84 -> 412 -> 2052 -> 22552 (crop [1:-1] -> cond[22550][128])
  k_upconv<<<dim3((412  +127)/128, 128), 128, 0, stream>>>(mels,        86,   1, up_w0, up_b0,
            ws+OF_BUFA,  80,   84, 11,  5, 3,   412, 0);
  k_upconv<<<dim3((2052 +127)/128, 128), 128, 0, stream>>>(ws+OF_BUFA, 412,   0, up_w1, up_b1,
            ws+OF_BUFB, 128,  412, 11,  5, 3,  2052, 0);
  k_upconv<<<dim3((22552+127)/128, 128), 128, 0, stream>>>(ws+OF_BUFB, 2052,  0, up_w2, up_b2,
            ws+OF_COND, 128, 2052, 23, 11, 6, 22552, 1);

  k_wavernn<<<NWG, NTHR, 0, stream>>>(Wx, bx, Wh, bh, O1w, O1b, O2w, O2b,
                                      O3w, O3b, O4w, O4b, ws, out);
}

// Round 7
// 334515.381 us; speedup vs baseline: 1.3870x; 1.1636x over previous
//
#include <hip/hip_runtime.h>
#include <math.h>

#define T_STEPS 22550
#define NWG 32
#define NTHR 256
#define GRID 256

typedef unsigned long long ull;

// ---- u64 slot indices (same layout for fast array and mirror array) ----
#define SL_H1   0          // [32][8]   h1 lower-half elems
#define SL_O1   256        // [32][16]  o1 rows
#define SL_AM1  768        // [32]      per-WG c-logit max
#define SL_H2   800        // [32][16]  h2 elems
#define SL_O3   1312       // [32][16]  o3 rows
#define SL_AM2  1824       // [2][32]   per-WG f-logit max, parity banks
#define SL_END  1888

// ---- float offsets in ws ----
#define OF_GEN   8                        // unsigned generation counter
#define OF_ELEC  16                       // int elec[8], winner at elec[8]
#define OF_SLOT  64                       // fast (sc0 / XCD-L2) slots
#define OF_MIR   (OF_SLOT + SL_END*2)     // agent-scope mirror slots
#define OF_AFTER (OF_MIR + SL_END*2)
#define OF_BUFA  OF_AFTER                 // conv stage0 out [128][412]
#define OF_BUFB  (OF_BUFA + 128*412)      // conv stage1 out [128][2052]
#define OF_COND  (OF_BUFB + 128*2052)     // cond [T][128]

__global__ void k_init(float* ws){
  int i = blockIdx.x*blockDim.x + threadIdx.x;
  int* elec = (int*)(ws + OF_ELEC);
  unsigned* gen = (unsigned*)(ws + OF_GEN);
  if (i < 8)  __hip_atomic_store(&elec[i], 0,  __ATOMIC_RELAXED, __HIP_MEMORY_SCOPE_AGENT);
  if (i == 8) __hip_atomic_store(&elec[8], -1, __ATOMIC_RELAXED, __HIP_MEMORY_SCOPE_AGENT);
  if (i == 9){
    unsigned gv = __hip_atomic_load(gen, __ATOMIC_RELAXED, __HIP_MEMORY_SCOPE_AGENT);
    __hip_atomic_store(gen, (gv + 1u) & 0x1FFFFu, __ATOMIC_RELAXED, __HIP_MEMORY_SCOPE_AGENT);
  }
  ull* sa = (ull*)(ws + OF_SLOT);
  ull* sb = (ull*)(ws + OF_MIR);
  if (i < SL_END){
    __hip_atomic_store(&sa[i], 0ULL, __ATOMIC_RELAXED, __HIP_MEMORY_SCOPE_AGENT);
    __hip_atomic_store(&sb[i], 0ULL, __ATOMIC_RELAXED, __HIP_MEMORY_SCOPE_AGENT);
  }
}

// transposed conv (lhs_dilation=sc), padding e, then relu.
// mode 0: y[c][j]; mode 1: write cond[t=j-1][c] (crop [1:-1], transpose)
__global__ void k_upconv(const float* __restrict__ x, int instride, int inoff,
                         const float* __restrict__ w, const float* __restrict__ b,
                         float* __restrict__ y, int Cin, int Lin, int K, int sc, int e,
                         int Lout, int mode)
{
  int j = blockIdx.x*blockDim.x + threadIdx.x;
  int c = blockIdx.y;
  if (j >= Lout) return;
  float acc = b[c];
  int kstart = ((e - j) % sc + sc) % sc;
  for (int i = 0; i < Cin; ++i){
    const float* wci = w + (c*Cin + i)*K;
    const float* xi  = x + i*instride + inoff;
    for (int k = kstart; k < K; k += sc){
      int qd = j - e + k;
      if (qd >= 0){
        int qq = qd / sc;
        if (qq < Lin) acc += wci[k]*xi[qq];
      }
    }
  }
  acc = fmaxf(acc, 0.f);
  if (mode == 0) y[c*Lout + j] = acc;
  else { int t = j - 1; if (t >= 0 && t < T_STEPS) y[t*128 + c] = acc; }
}

__device__ __forceinline__ float sigm(float x){ return 1.f/(1.f + expf(-x)); }

// ---- dual-path exchange: sc0 (XCD-L2 fast path, hypothesis) + agent mirror (proven) ----
__device__ __forceinline__ ull ld64_sc0(ull* p){
  ull r;
  asm volatile("global_load_dwordx2 %0, %1, off sc0\n\ts_waitcnt vmcnt(0)"
               : "=&v"(r) : "v"(p) : "memory");
  return r;
}
__device__ __forceinline__ void st64_sc0(ull* p, ull v){
  asm volatile("global_store_dwordx2 %0, %1, off sc0" :: "v"(p), "v"(v) : "memory");
}
__device__ __forceinline__ void pub_dual(ull* fast, ull* mir, ull pk){
  st64_sc0(fast, pk);
  __hip_atomic_store(mir, pk, __ATOMIC_RELAXED, __HIP_MEMORY_SCOPE_AGENT);
}
__device__ __forceinline__ ull spin_dual(ull* fast, ull* mir, unsigned tag, bool am){
  int it = 0;
  for (;;){
    ull pk = ((it & 3) == 3)
      ? __hip_atomic_load(mir, __ATOMIC_RELAXED, __HIP_MEMORY_SCOPE_AGENT)
      : ld64_sc0(fast);
    unsigned tg = am ? (unsigned)(pk & 0xFFFFFFu) : (unsigned)pk;
    if (tg == tag) return pk;
    ++it;
  }
}
__device__ __forceinline__ float spin_data(ull* fast, ull* mir, unsigned tag){
  ull pk = spin_dual(fast, mir, tag, false);
  return __uint_as_float((unsigned)(pk >> 32));
}

__launch_bounds__(NTHR)
__global__ void k_wavernn(const float* __restrict__ Wx, const float* __restrict__ bx,
                          const float* __restrict__ Wh, const float* __restrict__ bh,
                          const float* __restrict__ O1w, const float* __restrict__ O1b,
                          const float* __restrict__ O2w, const float* __restrict__ O2b,
                          const float* __restrict__ O3w, const float* __restrict__ O3b,
                          const float* __restrict__ O4w, const float* __restrict__ O4b,
                          float* ws, float* __restrict__ out)
{
  __shared__ __align__(16) float h_s[512];
  __shared__ __align__(16) float m_s[128];
  __shared__ __align__(16) float h1c_s[256];
  __shared__ __align__(16) float o_s[512];
  __shared__ float hg_s[48], xgb_s[48], xg1_s[48];
  __shared__ float red_s[8], sc_s[8];
  __shared__ float wc0_s[48], wc1_s[48], wc2_s[48], bx_s[48], bh_s[48];
  __shared__ int g_sh;
  __shared__ unsigned gen_sh;

  const int tid = threadIdx.x;

  // ---- same-XCD team election (MALL-level atomics, once per launch) ----
  if (tid == 0){
    unsigned xcc;
    asm volatile("s_getreg_b32 %0, hwreg(20, 0, 4)" : "=s"(xcc));  // HW_REG_XCC_ID
    int* elec = (int*)(ws + OF_ELEC);
    int slot = __hip_atomic_fetch_add(&elec[xcc & 7], 1,
                                      __ATOMIC_RELAXED, __HIP_MEMORY_SCOPE_AGENT);
    int mine = -1;
    if (slot < NWG){
      if (slot == NWG - 1){
        int expected = -1;
        __hip_atomic_compare_exchange_strong(&elec[8], &expected, (int)(xcc & 7),
            __ATOMIC_RELAXED, __ATOMIC_RELAXED, __HIP_MEMORY_SCOPE_AGENT);
      }
      int w;
      do { w = __hip_atomic_load(&elec[8], __ATOMIC_RELAXED, __HIP_MEMORY_SCOPE_AGENT); }
      while (w < 0);
      if (w == (int)(xcc & 7)) mine = slot;
    }
    g_sh = mine;
    gen_sh = __hip_atomic_load((unsigned*)(ws + OF_GEN),
                               __ATOMIC_RELAXED, __HIP_MEMORY_SCOPE_AGENT) & 0x1FFFFu;
  }
  __syncthreads();
  const int g = g_sh;
  if (g < 0) return;                     // not on the winning XCD team
  const unsigned gen = gen_sh;

  ull* sl = (ull*)(ws + OF_SLOT);
  ull* mr = (ull*)(ws + OF_MIR);
  const float* cond = ws + OF_COND;
  float* out_samp = out;
  float* out_log  = out + T_STEPS;

  // ---- preloads (ownership: WG g owns h elems {g+32i}; gate rows {gate*512+elem}) ----
  if (tid < 48){
    int row = (tid>>4)*512 + g + 32*(tid&15);
    wc0_s[tid] = Wx[(size_t)row*131 + 0];
    wc1_s[tid] = Wx[(size_t)row*131 + 1];
    wc2_s[tid] = Wx[(size_t)row*131 + 2];
    bx_s[tid]  = bx[row];
    bh_s[tid]  = bh[row];
  }
  // O1/O3: 16 rows/WG {g+32*m16}, 16 lanes/row, 16 contiguous cols/lane
  const int m16 = tid>>4, c16 = tid&15;
  const int rowO1 = g + 32*m16;
  float wO1r[16], wO3r[16];
  #pragma unroll
  for (int k=0;k<16;++k){
    wO1r[k] = O1w[(size_t)rowO1*256 + c16*16 + k];
    wO3r[k] = O3w[(size_t)rowO1*256 + c16*16 + k];
  }
  const float bO1r = O1b[rowO1], bO3r = O3b[rowO1];
  // O2/O4: 8 rows/WG {g+32*m8}, 32 lanes/row, stride-32 cols
  const int m8 = tid>>5, l32 = tid&31;
  const int row2 = g + 32*m8;
  float wO2r[16], wO4r[16];
  #pragma unroll
  for (int k=0;k<16;++k){
    wO2r[k] = O2w[(size_t)row2*512 + l32 + 32*k];
    wO4r[k] = O4w[(size_t)row2*512 + l32 + 32*k];
  }
  const float bO2 = O2b[row2], bO4 = O4b[row2];

  h_s[tid] = 0.f; h_s[tid+256] = 0.f;
  if (tid < 128) m_s[tid] = cond[tid];
  if (tid == 0){ sc_s[0] = 0.f; sc_s[1] = 0.f; }
  __syncthreads();

  // hg = Wh@h + bh ; xgb = Wx[:,3:]@m + bx   (48 rows x 4 lanes, bank-swizzled LDS reads)
  #define COMPUTE_HX() do { \
    if (tid < 192){ \
      const int li_ = tid>>2, q_ = tid&3; \
      const int row_ = (li_>>4)*512 + g + 32*(li_&15); \
      const float4* W4 = (const float4*)(Wh + (size_t)row_*512); \
      const float4* H4 = (const float4*)h_s; \
      float aH = 0.f; \
      _Pragma("unroll") \
      for (int kk=0; kk<32; ++kk){ \
        int f_ = q_*32 + ((kk + 2*q_) & 31); \
        float4 w = W4[f_], v = H4[f_]; \
        aH += w.x*v.x + w.y*v.y + w.z*v.z + w.w*v.w; \
      } \
      const float* WxR = Wx + (size_t)row_*131 + 3; \
      float aX = 0.f; \
      _Pragma("unroll") \
      for (int kk=0; kk<32; ++kk){ \
        int f_ = q_*32 + ((kk + 8*q_) & 31); \
        aX += WxR[f_]*m_s[f_]; \
      } \
      aH += __shfl_xor(aH,1); aH += __shfl_xor(aH,2); \
      aX += __shfl_xor(aX,1); aX += __shfl_xor(aX,2); \
      if (q_ == 0){ hg_s[li_] = aH + bh_s[li_]; xgb_s[li_] = aX + bx_s[li_]; } \
    } } while(0)

  COMPUTE_HX();

  for (int t = 0; t < T_STEPS; ++t){
    const unsigned tagD = (gen << 15) | (unsigned)(t + 1);                 // 32-bit data tag
    const unsigned tagA = ((gen & 0x1FFu) << 15) | (unsigned)(t + 1);      // 24-bit am tag
    __syncthreads();                        // hg/xgb/sc_s ready

    // (a) xg1 = xgb + c*w0 + f*w1
    if (tid < 48) xg1_s[tid] = xgb_s[tid] + sc_s[0]*wc0_s[tid] + sc_s[1]*wc1_s[tid];
    __syncthreads();

    // (b) GRU1 gates for own lower-8 elems, publish h1
    if (tid < 8){
      float r = sigm(xg1_s[tid]     + hg_s[tid]);
      float z = sigm(xg1_s[16+tid]  + hg_s[16+tid]);
      float n = tanhf(xg1_s[32+tid] + r*hg_s[32+tid]);
      float h1 = (1.f - z)*n + z*h_s[g + 32*tid];
      ull pk = ((ull)__float_as_uint(h1) << 32) | tagD;
      pub_dual(&sl[SL_H1 + g*8 + tid], &mr[SL_H1 + g*8 + tid], pk);
    }
    // (c) gather full h1[0:256]
    {
      int idx = SL_H1 + (tid & 31)*8 + (tid >> 5);
      h1c_s[tid] = spin_data(&sl[idx], &mr[idx], tagD);
    }
    __syncthreads();

    // (d) o1: own 16 rows, publish from reducing lane
    {
      float acc = 0.f;
      #pragma unroll
      for (int k=0;k<16;++k) acc += wO1r[k]*h1c_s[c16*16 + k];
      acc += __shfl_xor(acc,1); acc += __shfl_xor(acc,2);
      acc += __shfl_xor(acc,4); acc += __shfl_xor(acc,8);
      if (c16 == 0){
        ull pk = ((ull)__float_as_uint(fmaxf(acc + bO1r, 0.f)) << 32) | tagD;
        pub_dual(&sl[SL_O1 + g*16 + m16], &mr[SL_O1 + g*16 + m16], pk);
      }
    }
    // (e) gather o1
    {
      int i0 = SL_O1 + (tid & 31)*16 + (tid >> 5);
      o_s[tid]       = spin_data(&sl[i0],     &mr[i0],     tagD);
      o_s[tid + 256] = spin_data(&sl[i0 + 8], &mr[i0 + 8], tagD);
    }
    __syncthreads();

    // (f) O2 own 8 rows -> red_s; tid0 reduces + publishes am1
    {
      float acc = 0.f;
      #pragma unroll
      for (int k=0;k<16;++k) acc += wO2r[k]*o_s[l32 + 32*k];
      acc += __shfl_xor(acc,1); acc += __shfl_xor(acc,2); acc += __shfl_xor(acc,4);
      acc += __shfl_xor(acc,8); acc += __shfl_xor(acc,16);
      if (l32 == 0){ float v = acc + bO2; out_log[(size_t)t*512 + row2] = v; red_s[m8] = v; }
    }
    __syncthreads();
    if (tid == 0){
      float bv = red_s[0]; int bi = g;          // rows ascend with m -> strict > = first max
      #pragma unroll
      for (int m=1;m<8;++m){ float v = red_s[m]; if (v > bv){ bv = v; bi = g + 32*m; } }
      ull pk = ((ull)__float_as_uint(bv) << 32) | ((ull)(unsigned)bi << 24) | tagA;
      pub_dual(&sl[SL_AM1 + g], &mr[SL_AM1 + g], pk);
    }
    // (g) gather am1, global argmax -> c
    if (tid < 32){
      ull pk = spin_dual(&sl[SL_AM1 + tid], &mr[SL_AM1 + tid], tagA, true);
      float bv = __uint_as_float((unsigned)(pk >> 32));
      int   bi = (int)((pk >> 24) & 0xFFu);
      #pragma unroll
      for (int off=16; off>=1; off>>=1){
        float ov = __shfl_xor(bv,off); int oi = __shfl_xor(bi,off);
        if (ov > bv || (ov == bv && oi < bi)){ bv = ov; bi = oi; }
      }
      if (tid == 0){ sc_s[2] = (float)bi; sc_s[3] = (float)bi/127.5f - 1.f; }
    }
    __syncthreads();

    // (h) GRU2 for all 16 own elems, publish h2
    if (tid < 16){
      float cn = sc_s[3];
      float r = sigm(xg1_s[tid]     + cn*wc2_s[tid]     + hg_s[tid]);
      float z = sigm(xg1_s[16+tid]  + cn*wc2_s[16+tid]  + hg_s[16+tid]);
      float n = tanhf(xg1_s[32+tid] + cn*wc2_s[32+tid]  + r*hg_s[32+tid]);
      float h2 = (1.f - z)*n + z*h_s[g + 32*tid];
      ull pk = ((ull)__float_as_uint(h2) << 32) | tagD;
      pub_dual(&sl[SL_H2 + g*16 + tid], &mr[SL_H2 + g*16 + tid], pk);
    }
    __syncthreads();                        // old-h reads done before h_s overwrite
    // (i) gather h2 into h_s; next cond row
    {
      int i0 = SL_H2 + (tid & 31)*16 + (tid >> 5);
      h_s[tid]       = spin_data(&sl[i0],     &mr[i0],     tagD);
      h_s[tid + 256] = spin_data(&sl[i0 + 8], &mr[i0 + 8], tagD);
    }
    if (tid < 128 && t + 1 < T_STEPS) m_s[tid] = cond[(size_t)(t+1)*128 + tid];
    __syncthreads();

    // (j) o3: own 16 rows from h2 upper half, publish
    {
      float acc = 0.f;
      #pragma unroll
      for (int k=0;k<16;++k) acc += wO3r[k]*h_s[256 + c16*16 + k];
      acc += __shfl_xor(acc,1); acc += __shfl_xor(acc,2);
      acc += __shfl_xor(acc,4); acc += __shfl_xor(acc,8);
      if (c16 == 0){
        ull pk = ((ull)__float_as_uint(fmaxf(acc + bO3r, 0.f)) << 32) | tagD;
        pub_dual(&sl[SL_O3 + g*16 + m16], &mr[SL_O3 + g*16 + m16], pk);
      }
    }
    // (k) gather o3
    {
      int i0 = SL_O3 + (tid & 31)*16 + (tid >> 5);
      o_s[tid]       = spin_data(&sl[i0],     &mr[i0],     tagD);
      o_s[tid + 256] = spin_data(&sl[i0 + 8], &mr[i0 + 8], tagD);
    }
    __syncthreads();

    // (l) O4 own 8 rows -> red_s; tid0 publishes am2 (parity bank)
    {
      float acc = 0.f;
      #pragma unroll
      for (int k=0;k<16;++k) acc += wO4r[k]*o_s[l32 + 32*k];
      acc += __shfl_xor(acc,1); acc += __shfl_xor(acc,2); acc += __shfl_xor(acc,4);
      acc += __shfl_xor(acc,8); acc += __shfl_xor(acc,16);
      if (l32 == 0){ float v = acc + bO4; out_log[(size_t)t*512 + 256 + row2] = v; red_s[m8] = v; }
    }
    __syncthreads();
    if (tid == 0){
      float bv = red_s[0]; int bi = g;
      #pragma unroll
      for (int m=1;m<8;++m){ float v = red_s[m]; if (v > bv){ bv = v; bi = g + 32*m; } }
      ull pk = ((ull)__float_as_uint(bv) << 32) | ((ull)(unsigned)bi << 24) | tagA;
      int i0 = SL_AM2 + (t & 1)*32 + g;
      pub_dual(&sl[i0], &mr[i0], pk);
    }

    // (m) next step's hg/xgb — overlaps the am2 trip
    COMPUTE_HX();

    // (n) gather am2 -> f, carries, sample
    if (tid < 32){
      int i0 = SL_AM2 + (t & 1)*32 + tid;
      ull pk = spin_dual(&sl[i0], &mr[i0], tagA, true);
      float bv = __uint_as_float((unsigned)(pk >> 32));
      int   bi = (int)((pk >> 24) & 0xFFu);
      #pragma unroll
      for (int off=16; off>=1; off>>=1){
        float ov = __shfl_xor(bv,off); int oi = __shfl_xor(bi,off);
        if (ov > bv || (ov == bv && oi < bi)){ bv = ov; bi = oi; }
      }
      if (tid == 0){
        sc_s[0] = sc_s[3];                       // c carry
        sc_s[1] = (float)bi/127.5f - 1.f;        // f carry
        if (g == 0) out_samp[t] = (sc_s[2]*256.f + (float)bi)/32767.5f - 1.f;
      }
    }
    // loop-top __syncthreads() publishes hg/xgb/sc
  }
}

extern "C" void kernel_launch(void* const* d_in, const int* in_sizes, int n_in,
                              void* d_out, int out_size, void* d_ws, size_t ws_size,
                              hipStream_t stream)
{
  const float* mels  = (const float*)d_in[0];
  const float* up_w0 = (const float*)d_in[1]; const float* up_b0 = (const float*)d_in[2];
  const float* up_w1 = (const float*)d_in[3]; const float* up_b1 = (const float*)d_in[4];
  const float* up_w2 = (const float*)d_in[5]; const float* up_b2 = (const float*)d_in[6];
  const float* Wx  = (const float*)d_in[7];  const float* bx  = (const float*)d_in[8];
  const float* Wh  = (const float*)d_in[9];  const float* bh  = (const float*)d_in[10];
  const float* O1w = (const float*)d_in[11]; const float* O1b = (const float*)d_in[12];
  const float* O2w = (const float*)d_in[13]; const float* O2b = (const float*)d_in[14];
  const float* O3w = (const float*)d_in[15]; const float* O3b = (const float*)d_in[16];
  const float* O4w = (const float*)d_in[17]; const float* O4b = (const float*)d_in[18];
  float* ws  = (float*)d_ws;
  float* out = (float*)d_out;

  k_init<<<8, 256, 0, stream>>>(ws);

  // upsample: 84 -> 412 -> 2052 -> 22552 (crop [1:-1] -> cond[22550][128])
  k_upconv<<<dim3((412  +127)/128, 128), 128, 0, stream>>>(mels,        86,   1, up_w0, up_b0,
            ws+OF_BUFA,  80,   84, 11,  5, 3,   412, 0);
  k_upconv<<<dim3((2052 +127)/128, 128), 128, 0, stream>>>(ws+OF_BUFA, 412,   0, up_w1, up_b1,
            ws+OF_BUFB, 128,  412, 11,  5, 3,  2052, 0);
  k_upconv<<<dim3((22552+127)/128, 128), 128, 0, stream>>>(ws+OF_BUFB, 2052,  0, up_w2, up_b2,
            ws+OF_COND, 128, 2052, 23, 11, 6, 22552, 1);

  k_wavernn<<<GRID, NTHR, 0, stream>>>(Wx, bx, Wh, bh, O1w, O1b, O2w, O2b,
                                       O3w, O3b, O4w, O4b, ws, out);
}